// Round 1
// baseline (226.743 us; speedup 1.0000x reference)
//
#include <hip/hip_runtime.h>

// OneDilate: out[b,c,i,j] = sum_{10x10 window} (1 - x_clamped)*0.5
// Separable box filter: horizontal 10-sum then vertical 10-sum,
// replicate-pad handled by clamping source indices.

#define IMG_H 512
#define IMG_W 512
#define OUT_H 511
#define OUT_W 511
#define KS 10
#define MEAN 4
#define TILE_H 32
#define TILE_W 64
#define IN_TH (TILE_H + KS - 1)   // 41
#define IN_TW (TILE_W + KS - 1)   // 73
#define IN_TW_PAD (IN_TW + 1)     // 74 (avoid pow2-ish stride issues)

__global__ __launch_bounds__(256) void onedilate_kernel(
    const float* __restrict__ x, float* __restrict__ out)
{
    __shared__ float sIn[IN_TH][IN_TW_PAD];  // input tile with halo
    __shared__ float sH[IN_TH][TILE_W];      // horizontal sums

    const int tid = threadIdx.x;
    const int j0 = blockIdx.x * TILE_W;      // output col origin
    const int i0 = blockIdx.y * TILE_H;      // output row origin
    const int bc = blockIdx.z;               // b*C + c

    const float* __restrict__ xim = x + (size_t)bc * IMG_H * IMG_W;
    float* __restrict__ oim = out + (size_t)bc * OUT_H * OUT_W;

    // Phase 1: stage (1-x)*0.5 with clamp-to-edge into LDS.
    // 41*73 = 2993 elements; ~12 per thread; row-major -> coalesced.
    for (int idx = tid; idx < IN_TH * IN_TW; idx += 256) {
        int r = idx / IN_TW;
        int c = idx - r * IN_TW;
        int gr = min(max(i0 + r - MEAN, 0), IMG_H - 1);
        int gc = min(max(j0 + c - MEAN, 0), IMG_W - 1);
        sIn[r][c] = (1.0f - xim[gr * IMG_W + gc]) * 0.5f;
    }
    __syncthreads();

    // Phase 2: horizontal 10-sum. 41*64 = 2624 elements.
    // lanes 0..63 share a row, consecutive c -> stride-1 LDS (2-way, free).
    for (int idx = tid; idx < IN_TH * TILE_W; idx += 256) {
        int r = idx >> 6;              // / TILE_W
        int c = idx & (TILE_W - 1);
        float s = 0.0f;
        #pragma unroll
        for (int k = 0; k < KS; ++k) s += sIn[r][c + k];
        sH[r][c] = s;
    }
    __syncthreads();

    // Phase 3: vertical 10-sum + store. 32*64 = 2048 outputs.
    for (int idx = tid; idx < TILE_H * TILE_W; idx += 256) {
        int r = idx >> 6;
        int c = idx & (TILE_W - 1);
        int gr = i0 + r, gc = j0 + c;
        if (gr < OUT_H && gc < OUT_W) {
            float s = 0.0f;
            #pragma unroll
            for (int k = 0; k < KS; ++k) s += sH[r + k][c];
            oim[gr * OUT_W + gc] = s;
        }
    }
}

extern "C" void kernel_launch(void* const* d_in, const int* in_sizes, int n_in,
                              void* d_out, int out_size, void* d_ws, size_t ws_size,
                              hipStream_t stream) {
    const float* x = (const float*)d_in[0];
    float* out = (float*)d_out;

    dim3 block(256, 1, 1);
    dim3 grid((OUT_W + TILE_W - 1) / TILE_W,   // 8
              (OUT_H + TILE_H - 1) / TILE_H,   // 16
              32 * 3);                         // 96 images
    onedilate_kernel<<<grid, block, 0, stream>>>(x, out);
}

// Round 2
// 220.644 us; speedup vs baseline: 1.0276x; 1.0276x over previous
//
#include <hip/hip_runtime.h>

// OneDilate: out[b,c,i,j] = sum_{10x10 window} (1 - x_clamped)*0.5
// Separable box filter with sliding-window register sums:
//   phase 1: stage (1-x)*0.5 tile+halo into LDS (clamped indices)
//   phase A: horizontal 10-sum, 1 thread per (row, 16-col segment),
//            ds_read_b128 x7 -> sliding window -> ds_write_b128 x4
//   phase B: vertical 10-sum, 1 thread per (column, 8-row run),
//            17 scalar LDS reads -> sliding window -> coalesced stores

#define IMG_H 512
#define IMG_W 512
#define OUT_H 511
#define OUT_W 511
#define KS 10
#define MEAN 4
#define TILE_H 32
#define TILE_W 64
#define IN_TH (TILE_H + KS - 1)   // 41
#define IN_TW (TILE_W + KS - 1)   // 73
#define IN_TW_PAD 76              // pad to multiple of 4 floats (16B) for b128
#define SH_PAD 68                 // sH row stride, multiple of 4 floats

__global__ __launch_bounds__(256) void onedilate_kernel(
    const float* __restrict__ x, float* __restrict__ out)
{
    __shared__ __align__(16) float sIn[IN_TH][IN_TW_PAD];  // 41*76*4 = 12464 B
    __shared__ __align__(16) float sH[IN_TH][SH_PAD];      // 41*68*4 = 11152 B

    const int tid = threadIdx.x;
    const int j0 = blockIdx.x * TILE_W;      // output col origin
    const int i0 = blockIdx.y * TILE_H;      // output row origin
    const int bc = blockIdx.z;               // b*C + c

    const float* __restrict__ xim = x + (size_t)bc * IMG_H * IMG_W;
    float* __restrict__ oim = out + (size_t)bc * OUT_H * OUT_W;

    // Phase 1: stage (1-x)*0.5 with clamp-to-edge into LDS.
    // 41*73 = 2993 elements; row-major -> coalesced global loads.
    for (int idx = tid; idx < IN_TH * IN_TW; idx += 256) {
        int r = idx / IN_TW;
        int c = idx - r * IN_TW;
        int gr = min(max(i0 + r - MEAN, 0), IMG_H - 1);
        int gc = min(max(j0 + c - MEAN, 0), IMG_W - 1);
        sIn[r][c] = (1.0f - xim[gr * IMG_W + gc]) * 0.5f;
    }
    __syncthreads();

    // Phase A: horizontal sliding 10-sum.
    // 41 rows x 4 segments of 16 outputs = 164 threads active.
    if (tid < IN_TH * 4) {
        int r = tid >> 2;
        int s = tid & 3;
        const float* rowp = &sIn[r][s * 16];
        float w[28];
        #pragma unroll
        for (int k = 0; k < 7; ++k) {
            float4 v = *(const float4*)(rowp + k * 4);
            w[k*4+0] = v.x; w[k*4+1] = v.y; w[k*4+2] = v.z; w[k*4+3] = v.w;
        }
        float hs[16];
        float acc = 0.0f;
        #pragma unroll
        for (int k = 0; k < KS; ++k) acc += w[k];
        hs[0] = acc;
        #pragma unroll
        for (int i = 1; i < 16; ++i) {
            acc += w[i + 9] - w[i - 1];
            hs[i] = acc;
        }
        float* op = &sH[r][s * 16];
        #pragma unroll
        for (int k = 0; k < 4; ++k) {
            float4 v = make_float4(hs[k*4+0], hs[k*4+1], hs[k*4+2], hs[k*4+3]);
            *(float4*)(op + k * 4) = v;
        }
    }
    __syncthreads();

    // Phase B: vertical sliding 10-sum + coalesced stores.
    // Thread -> column c = tid&63, row run r0 = (tid>>6)*8 (8 outputs).
    {
        int c = tid & 63;
        int r0 = (tid >> 6) * 8;
        float col[17];
        #pragma unroll
        for (int k = 0; k < 17; ++k) col[k] = sH[r0 + k][c];
        float vs = 0.0f;
        #pragma unroll
        for (int k = 0; k < KS; ++k) vs += col[k];
        int gc = j0 + c;
        if (gc < OUT_W) {
            #pragma unroll
            for (int rr = 0; rr < 8; ++rr) {
                int gr = i0 + r0 + rr;
                if (gr < OUT_H) oim[gr * OUT_W + gc] = vs;
                if (rr < 7) vs += col[rr + 10] - col[rr];
            }
        }
    }
}

extern "C" void kernel_launch(void* const* d_in, const int* in_sizes, int n_in,
                              void* d_out, int out_size, void* d_ws, size_t ws_size,
                              hipStream_t stream) {
    const float* x = (const float*)d_in[0];
    float* out = (float*)d_out;

    dim3 block(256, 1, 1);
    dim3 grid((OUT_W + TILE_W - 1) / TILE_W,   // 8
              (OUT_H + TILE_H - 1) / TILE_H,   // 16
              32 * 3);                         // 96 images
    onedilate_kernel<<<grid, block, 0, stream>>>(x, out);
}

// Round 3
// 215.622 us; speedup vs baseline: 1.0516x; 1.0233x over previous
//
#include <hip/hip_runtime.h>

// OneDilate: out[b,c,i,j] = sum_{10x10 clamped window} (1 - x)*0.5
//          = 50 - 0.5 * sum_{10x10 clamped window} x
// Row-streaming register kernel: no LDS, no barriers.
// Thread = one output column; block = 256 cols x 64-output-row band.
// Per streamed row: 10 coalesced loads (L1-hot), horizontal 10-sum,
// 10-deep static register ring + running vertical sum, coalesced store.

#define IMG 512
#define OUTW 511
#define KS 10
#define MEAN 4
#define BAND 64                       // output rows per block
#define TSTREAM (BAND + KS - 1)       // 73 streamed rows

__global__ __launch_bounds__(256, 8) void onedilate_kernel(
    const float* __restrict__ x, float* __restrict__ out)
{
    const int t = threadIdx.x;
    const int c = blockIdx.x * 256 + t;      // output col 0..511 (511 unused)
    const int rb = blockIdx.y * BAND;        // output row base
    const int bc = blockIdx.z;               // b*C + c

    const float* __restrict__ xim = x + (size_t)bc * IMG * IMG;
    float* __restrict__ oim = out + (size_t)bc * OUTW * OUTW;

    // Clamped column offsets — loop-invariant, computed once.
    int cc[KS];
    #pragma unroll
    for (int k = 0; k < KS; ++k)
        cc[k] = min(max(c - MEAN + k, 0), IMG - 1);

    float h[KS];                              // ring of horizontal sums
    #pragma unroll
    for (int k = 0; k < KS; ++k) h[k] = 0.0f;
    float V = 0.0f;                           // running vertical sum

    const bool cok = (c < OUTW);

    // Outer loop stride KS so ring indices are compile-time constants.
    for (int t0 = 0; t0 < TSTREAM; t0 += KS) {
        #pragma unroll
        for (int u = 0; u < KS; ++u) {
            int s = t0 + u;                   // block-uniform -> scalar branch
            if (s < TSTREAM) {
                int ri = min(max(rb + s - MEAN, 0), IMG - 1);  // uniform row
                const float* __restrict__ rowp = xim + ri * IMG;
                float H = 0.0f;
                #pragma unroll
                for (int k = 0; k < KS; ++k) H += rowp[cc[k]];
                V += H - h[u];
                h[u] = H;
                int i = rb + s - (KS - 1);    // output row
                if (s >= KS - 1 && i < OUTW && cok)
                    oim[i * OUTW + c] = 50.0f - 0.5f * V;
            }
        }
    }
}

extern "C" void kernel_launch(void* const* d_in, const int* in_sizes, int n_in,
                              void* d_out, int out_size, void* d_ws, size_t ws_size,
                              hipStream_t stream) {
    const float* x = (const float*)d_in[0];
    float* out = (float*)d_out;

    dim3 block(256, 1, 1);
    dim3 grid(2,                // col tiles: 2 x 256 >= 511
              IMG / BAND,      // 8 row bands
              32 * 3);         // 96 images
    onedilate_kernel<<<grid, block, 0, stream>>>(x, out);
}

// Round 4
// 190.473 us; speedup vs baseline: 1.1904x; 1.1320x over previous
//
#include <hip/hip_runtime.h>

// OneDilate: out[b,c,i,j] = sum_{10x10 clamped window} (1 - x)*0.5
//          = 50 - 0.5 * sum_{10x10 clamped window} x
// Register-streaming, no LDS/barriers. Thread owns 4 consecutive output
// cols x 32-row band. Per streamed row: 3 aligned float4 loads + 1 scalar
// (13 floats cover cols 4j-4..4j+8), sliding horizontal sums, 10-deep
// float4 ring + running vertical sum, 4 scalar stores.

#define IMG 512
#define OUTW 511
#define KS 10
#define MEAN 4
#define SUB 32                  // output rows per thread
#define TSTREAM (SUB + KS - 1)  // 41 streamed rows

__global__ __launch_bounds__(256) void onedilate_kernel(
    const float* __restrict__ x, float* __restrict__ out)
{
    const int tid = threadIdx.x;
    const int j   = tid & 127;          // col group: output cols 4j..4j+3
    const int sub = tid >> 7;           // row sub-band 0/1 (wave-uniform)
    const int rb  = blockIdx.x * 64 + sub * SUB;   // output row base
    const int bc  = blockIdx.y;                    // b*C + c

    const float* __restrict__ xim = x + (size_t)bc * IMG * IMG;
    float* __restrict__ oim = out + (size_t)bc * OUTW * OUTW;

    // Per-thread constant load bases + edge flags (branchless clamp).
    const int b0  = 4 * j - 4;                    // k=0 base (only j=0 is OOB-low)
    const int bl0 = max(b0, 0);
    const int b2  = 4 * j + 4;                    // k=2 base (only j=127 OOB-high)
    const int bl2 = min(b2, IMG - 4);
    const bool lo0 = (b0 < 0);
    const bool hi2 = (b2 > IMG - 4);
    const int c12 = min(4 * j + 8, IMG - 1);      // the 13th float, clamped

    float4 ring[KS];
    #pragma unroll
    for (int k = 0; k < KS; ++k) ring[k] = make_float4(0.f, 0.f, 0.f, 0.f);
    float4 V = make_float4(0.f, 0.f, 0.f, 0.f);

    const int cbase = 4 * j;

    for (int t0 = 0; t0 < TSTREAM; t0 += KS) {
        #pragma unroll
        for (int u = 0; u < KS; ++u) {
            int s = t0 + u;                       // scalar
            if (s < TSTREAM) {
                int ri = min(max(rb + s - MEAN, 0), IMG - 1);
                const float* __restrict__ rowp = xim + ri * IMG;

                float4 v0 = *(const float4*)(rowp + bl0);
                float4 v1 = *(const float4*)(rowp + cbase);   // always in-bounds
                float4 v2 = *(const float4*)(rowp + bl2);
                float w12 = rowp[c12];
                if (lo0) v0 = make_float4(v0.x, v0.x, v0.x, v0.x);  // replicate col 0
                if (hi2) v2 = make_float4(v2.w, v2.w, v2.w, v2.w);  // replicate col 511

                // Horizontal sliding 10-sums for 4 outputs.
                float S = v0.x + v0.y + v0.z + v0.w
                        + v1.x + v1.y + v1.z + v1.w
                        + v2.x + v2.y;
                float4 H;
                H.x = S;
                S += v2.z - v0.x; H.y = S;
                S += v2.w - v0.y; H.z = S;
                S += w12  - v0.z; H.w = S;

                // Vertical ring update.
                V.x += H.x - ring[u].x;
                V.y += H.y - ring[u].y;
                V.z += H.z - ring[u].z;
                V.w += H.w - ring[u].w;
                ring[u] = H;

                if (s >= KS - 1) {
                    int i = rb + s - (KS - 1);
                    if (i < OUTW) {
                        float* op = oim + (size_t)i * OUTW + cbase;
                        op[0] = 50.0f - 0.5f * V.x;
                        op[1] = 50.0f - 0.5f * V.y;
                        op[2] = 50.0f - 0.5f * V.z;
                        if (cbase + 3 < OUTW) op[3] = 50.0f - 0.5f * V.w;
                    }
                }
            }
        }
    }
}

extern "C" void kernel_launch(void* const* d_in, const int* in_sizes, int n_in,
                              void* d_out, int out_size, void* d_ws, size_t ws_size,
                              hipStream_t stream) {
    const float* x = (const float*)d_in[0];
    float* out = (float*)d_out;

    dim3 block(256, 1, 1);
    dim3 grid(IMG / 64,     // 8 bands of 64 rows (2 sub-bands of 32 per block)
              32 * 3,       // 96 images
              1);
    onedilate_kernel<<<grid, block, 0, stream>>>(x, out);
}